// Round 1
// baseline (139.138 us; speedup 1.0000x reference)
//
#include <hip/hip_runtime.h>

#define K_SIGN 1000.0f
#define EPSILON 5.0f

// ws layout (floats): mx[N] | se[N] | S[N] | C(double, 8B aligned)

__global__ void k_init(float* mx, float* se, double* C, float* out, int n) {
    int i = blockIdx.x * blockDim.x + threadIdx.x;
    if (i < n) { mx[i] = 0.0f; se[i] = 0.0f; out[i] = 0.0f; }
    if (i == 0) *C = 0.0;
}

// segment max of contrib = log(p[src]) + p[dst]*log_n  (contrib > 0 always,
// so int-bits atomicMax on float is order-preserving; init 0.0f works)
__global__ void k_max(const int* __restrict__ src, const int* __restrict__ dst,
                      const float* __restrict__ p, float* mx,
                      int e, int n, float log_n) {
    int t = blockIdx.x * blockDim.x + threadIdx.x;
    if (t >= e + n) return;
    int s = (t < e) ? src[t] : (t - e);
    int d = (t < e) ? dst[t] : (t - e);
    float contrib = logf(p[s]) + p[d] * log_n;
    atomicMax((int*)&mx[d], __float_as_int(contrib));
}

__global__ void k_sumexp(const int* __restrict__ src, const int* __restrict__ dst,
                         const float* __restrict__ p, const float* __restrict__ mx,
                         float* se, int e, int n, float log_n) {
    int t = blockIdx.x * blockDim.x + threadIdx.x;
    if (t >= e + n) return;
    int s = (t < e) ? src[t] : (t - e);
    int d = (t < e) ? dst[t] : (t - e);
    float contrib = logf(p[s]) + p[d] * log_n;
    atomicAdd(&se[d], expf(contrib - mx[d]));
}

// C = dot(x, p), accumulated in double for stability (then rounded to f32 use)
__global__ void k_dot(const float* __restrict__ x, const float* __restrict__ p,
                      double* C, int n) {
    __shared__ double lds[4];  // one slot per wave (256 threads = 4 waves)
    int tid = threadIdx.x;
    int stride = gridDim.x * blockDim.x;
    double acc = 0.0;
    for (int i = blockIdx.x * blockDim.x + tid; i < n; i += stride)
        acc += (double)x[i] * (double)p[i];
    // wave reduce (64 lanes)
    for (int off = 32; off > 0; off >>= 1)
        acc += __shfl_down(acc, off, 64);
    int wave = tid >> 6;
    if ((tid & 63) == 0) lds[wave] = acc;
    __syncthreads();
    if (tid == 0) {
        double b = lds[0] + lds[1] + lds[2] + lds[3];
        atomicAdd(C, b);
    }
}

__global__ void k_S(const float* __restrict__ mx, const float* __restrict__ se,
                    const double* __restrict__ C, float* S, int n) {
    int i = blockIdx.x * blockDim.x + threadIdx.x;
    if (i < n) {
        float c = (float)(*C);
        S[i] = (mx[i] + logf(se[i])) + c;  // matches ref: (mx + log(se)) + dot
    }
}

// out[i] = sum_j tanh(K*(S_i - S_j) - EPS); 256x256 tiles, S_j chunk in LDS
__global__ void __launch_bounds__(256) k_pair(const float* __restrict__ S,
                                              float* out, int n) {
    __shared__ float sj[256];
    int tid = threadIdx.x;
    int i = blockIdx.x * 256 + tid;
    int jbase = blockIdx.y * 256;
    sj[tid] = S[jbase + tid];
    __syncthreads();
    float si = S[i];
    float acc = 0.0f;
#pragma unroll 8
    for (int j = 0; j < 256; ++j) {
        float t = fmaf(K_SIGN, si - sj[j], -EPSILON);
        acc += tanhf(t);
    }
    atomicAdd(&out[i], acc);
}

extern "C" void kernel_launch(void* const* d_in, const int* in_sizes, int n_in,
                              void* d_out, int out_size, void* d_ws, size_t ws_size,
                              hipStream_t stream) {
    const int* edge_index = (const int*)d_in[0];
    const float* p = (const float*)d_in[1];
    const float* x = (const float*)d_in[2];
    float* out = (float*)d_out;

    int e = in_sizes[0] / 2;
    int n = in_sizes[1];
    const int* src = edge_index;        // row 0
    const int* dst = edge_index + e;    // row 1

    float* mx = (float*)d_ws;
    float* se = mx + n;
    float* S  = se + n;
    double* C = (double*)(S + n);       // 8-byte aligned: 3n*4 bytes, n even

    float log_n = logf((float)n);

    int threads = 256;
    int gN  = (n + threads - 1) / threads;
    int gEN = (e + n + threads - 1) / threads;

    k_init<<<gN, threads, 0, stream>>>(mx, se, C, out, n);
    k_max<<<gEN, threads, 0, stream>>>(src, dst, p, mx, e, n, log_n);
    k_sumexp<<<gEN, threads, 0, stream>>>(src, dst, p, mx, se, e, n, log_n);
    k_dot<<<64, threads, 0, stream>>>(x, p, C, n);
    k_S<<<gN, threads, 0, stream>>>(mx, se, C, S, n);

    dim3 pg(n / 256, n / 256);
    k_pair<<<pg, 256, 0, stream>>>(S, out, n);
}

// Round 2
// 118.802 us; speedup vs baseline: 1.1712x; 1.1712x over previous
//
#include <hip/hip_runtime.h>

#define K_SIGN 1000.0f
#define EPSILON 5.0f

// ws layout: pmax[N] (int) | T[N] (int) | C (double, 8B-aligned at offset 2N*4)

// Zero the accumulators + output; block 0 alone computes C = dot(x,p) in double
// (single writer -> no init/atomic race).
__global__ void k_init(int* pmax, int* T, double* C, float* out,
                       const float* __restrict__ x, const float* __restrict__ p,
                       int n) {
    int tid = threadIdx.x;
    int gid = blockIdx.x * blockDim.x + tid;
    int stride = gridDim.x * blockDim.x;
    for (int i = gid; i < n; i += stride) {
        pmax[i] = 0;
        T[i] = 0;
        out[i] = 0.0f;
    }
    if (blockIdx.x == 0) {
        __shared__ double lds[4];
        double acc = 0.0;
        for (int i = tid; i < n; i += blockDim.x)
            acc += (double)x[i] * (double)p[i];
        for (int off = 32; off > 0; off >>= 1)
            acc += __shfl_down(acc, off, 64);
        if ((tid & 63) == 0) lds[tid >> 6] = acc;
        __syncthreads();
        if (tid == 0) *C = lds[0] + lds[1] + lds[2] + lds[3];
    }
}

// Single pass over E edges + N self-loops:
//   pmax[d] = max p[src]  (int atomicMax; log is monotone so
//             log(pmax)+p[d]*log_n bitwise-matches the reference's segment max)
//   T[d]    = sum p[src]  (exact integer sum; se = T/pmax)
__global__ void k_edge(const int* __restrict__ src, const int* __restrict__ dst,
                       const float* __restrict__ p, int* pmax, int* T,
                       int e, int n) {
    int t = blockIdx.x * blockDim.x + threadIdx.x;
    if (t >= e + n) return;
    int s = (t < e) ? src[t] : (t - e);
    int d = (t < e) ? dst[t] : (t - e);
    int ps = (int)p[s];
    atomicMax(&pmax[d], ps);
    atomicAdd(&T[d], ps);
}

// out[i] = sum_j tanh(K*(S_i - S_j) - EPS), S computed in-tile from pmax/T/p/C.
// tanh(t) = 1 - 2/(1+exp(2t)):  sum over 256 j = 256 - 2*sum r, r = 1/(1+e^{2t}).
__global__ void __launch_bounds__(256) k_pair(const int* __restrict__ pmax,
                                              const int* __restrict__ T,
                                              const float* __restrict__ p,
                                              const double* __restrict__ C,
                                              float* out, float log_n) {
    __shared__ float sj[256];
    int tid = threadIdx.x;
    int i  = blockIdx.x * 256 + tid;
    int jn = blockIdx.y * 256 + tid;
    float c = (float)(*C);

    // S for this block's j-node -> LDS
    {
        float pm = (float)pmax[jn];
        float mx = logf(pm) + p[jn] * log_n;       // == reference segment max
        float se = (float)T[jn] / pm;
        sj[tid] = (mx + logf(se)) + c;
    }
    // S for this block's i-node -> register
    float si;
    {
        float pm = (float)pmax[i];
        float mx = logf(pm) + p[i] * log_n;
        float se = (float)T[i] / pm;
        si = (mx + logf(se)) + c;
    }
    __syncthreads();

    const float A = 2.0f * K_SIGN;    // 2K
    const float B = -2.0f * EPSILON;  // -2*EPS
    float acc = 0.0f;
    const float4* sj4 = (const float4*)sj;
#pragma unroll 8
    for (int j4 = 0; j4 < 64; ++j4) {
        float4 v = sj4[j4];
        float t0 = fmaf(si - v.x, A, B);
        float t1 = fmaf(si - v.y, A, B);
        float t2 = fmaf(si - v.z, A, B);
        float t3 = fmaf(si - v.w, A, B);
        acc += __fdividef(1.0f, 1.0f + __expf(t0));
        acc += __fdividef(1.0f, 1.0f + __expf(t1));
        acc += __fdividef(1.0f, 1.0f + __expf(t2));
        acc += __fdividef(1.0f, 1.0f + __expf(t3));
    }
    atomicAdd(&out[i], fmaf(-2.0f, acc, 256.0f));
}

extern "C" void kernel_launch(void* const* d_in, const int* in_sizes, int n_in,
                              void* d_out, int out_size, void* d_ws, size_t ws_size,
                              hipStream_t stream) {
    const int* edge_index = (const int*)d_in[0];
    const float* p = (const float*)d_in[1];
    const float* x = (const float*)d_in[2];
    float* out = (float*)d_out;

    int e = in_sizes[0] / 2;
    int n = in_sizes[1];
    const int* src = edge_index;       // row 0
    const int* dst = edge_index + e;   // row 1

    int* pmax = (int*)d_ws;
    int* T = pmax + n;
    double* C = (double*)(T + n);      // offset 2n*4 bytes, 8B-aligned (n even)

    float log_n = logf((float)n);

    int threads = 256;
    int gEN = (e + n + threads - 1) / threads;

    k_init<<<32, threads, 0, stream>>>(pmax, T, C, out, x, p, n);
    k_edge<<<gEN, threads, 0, stream>>>(src, dst, p, pmax, T, e, n);

    dim3 pg(n / 256, n / 256);
    k_pair<<<pg, 256, 0, stream>>>(pmax, T, p, C, out, log_n);
}

// Round 3
// 107.509 us; speedup vs baseline: 1.2942x; 1.1050x over previous
//
#include <hip/hip_runtime.h>

#define K_SIGN 1000.0f
#define EPSILON 5.0f

// Band: tanhf(K*d - EPS) is EXACTLY +-1.0f for |K*d - EPS| >= 12.
#define D_HI ((EPSILON + 12.0f) / K_SIGN)   // d > D_HI  -> +1.0f exactly
#define D_LO ((EPSILON - 12.0f) / K_SIGN)   // d < D_LO  -> -1.0f exactly

// ws layout: T[N] (int) | C (double, 8B-aligned at offset N*4)

// T[i] = p[i] (self-loop contribution), out[i] = 0; block 0 computes
// C = dot(x,p) in double (single writer).
__global__ void k_init(int* T, double* C, float* out,
                       const float* __restrict__ x, const float* __restrict__ p,
                       int n) {
    int tid = threadIdx.x;
    int gid = blockIdx.x * blockDim.x + tid;
    int stride = gridDim.x * blockDim.x;
    for (int i = gid; i < n; i += stride) {
        T[i] = (int)p[i];
        out[i] = 0.0f;
    }
    if (blockIdx.x == 0) {
        __shared__ double lds[4];
        double acc = 0.0;
        for (int i = tid; i < n; i += blockDim.x)
            acc += (double)x[i] * (double)p[i];
        for (int off = 32; off > 0; off >>= 1)
            acc += __shfl_down(acc, off, 64);
        if ((tid & 63) == 0) lds[tid >> 6] = acc;
        __syncthreads();
        if (tid == 0) *C = lds[0] + lds[1] + lds[2] + lds[3];
    }
}

// T[dst] += p[src]  (exact integer segment sum). Note the segment max cancels:
// mx + log(se) = log(pmax) + log(T/pmax) = log(T), so T alone determines S.
__global__ void k_edge(const int* __restrict__ src, const int* __restrict__ dst,
                       const float* __restrict__ p, int* T, int e) {
    int t = blockIdx.x * blockDim.x + threadIdx.x;
    if (t >= e) return;
    atomicAdd(&T[dst[t]], (int)p[src[t]]);
}

// out[i] = sum_j tanh(K*(S_i - S_j) - EPS), S = log(T) + p*log_n + C.
// Out-of-band pairs contribute exactly +-1.0f (counted); in-band pairs
// (rare: diagonal + near-ties) take a ballot-guarded tanhf slow path.
__global__ void __launch_bounds__(256) k_pair(const int* __restrict__ T,
                                              const float* __restrict__ p,
                                              const double* __restrict__ C,
                                              float* out, float log_n) {
    __shared__ float sj[256];
    int tid = threadIdx.x;
    int i  = blockIdx.x * 256 + tid;
    int jn = blockIdx.y * 256 + tid;
    float c = (float)(*C);

    sj[tid] = (logf((float)T[jn]) + p[jn] * log_n) + c;
    float si = (logf((float)T[i]) + p[i] * log_n) + c;
    __syncthreads();

    float acc = 0.0f;
    const float4* sj4 = (const float4*)sj;
#pragma unroll 4
    for (int j4 = 0; j4 < 64; ++j4) {
        float4 v = sj4[j4];
#pragma unroll
        for (int u = 0; u < 4; ++u) {
            float svj = (u == 0) ? v.x : (u == 1) ? v.y : (u == 2) ? v.z : v.w;
            float d = si - svj;
            bool band = (d <= D_HI) & (d >= D_LO);
            acc += (d > D_HI) ? 1.0f : 0.0f;
            acc -= (d < D_LO) ? 1.0f : 0.0f;
            if (__ballot(band)) {            // rare: diagonal tiles + near-ties
                if (band)
                    acc += tanhf(fmaf(K_SIGN, d, -EPSILON));
            }
        }
    }
    atomicAdd(&out[i], acc);
}

extern "C" void kernel_launch(void* const* d_in, const int* in_sizes, int n_in,
                              void* d_out, int out_size, void* d_ws, size_t ws_size,
                              hipStream_t stream) {
    const int* edge_index = (const int*)d_in[0];
    const float* p = (const float*)d_in[1];
    const float* x = (const float*)d_in[2];
    float* out = (float*)d_out;

    int e = in_sizes[0] / 2;
    int n = in_sizes[1];
    const int* src = edge_index;       // row 0
    const int* dst = edge_index + e;   // row 1

    int* T = (int*)d_ws;
    double* C = (double*)(T + n);      // offset n*4 bytes, 8B-aligned (n even)

    float log_n = logf((float)n);

    int threads = 256;
    int gE = (e + threads - 1) / threads;

    k_init<<<32, threads, 0, stream>>>(T, C, out, x, p, n);
    k_edge<<<gE, threads, 0, stream>>>(src, dst, p, T, e);

    dim3 pg(n / 256, n / 256);
    k_pair<<<pg, 256, 0, stream>>>(T, p, C, out, log_n);
}